// Round 4
// baseline (123.756 us; speedup 1.0000x reference)
//
#include <hip/hip_runtime.h>
#include <cstdint>
#include <cstddef>

typedef __bf16 bf16;
typedef __bf16 bf16x8 __attribute__((ext_vector_type(8)));
typedef float  f32x4  __attribute__((ext_vector_type(4)));

#define MFMA16(a,b,c) __builtin_amdgcn_mfma_f32_16x16x32_bf16((a),(b),(c),0,0,0)

__device__ __forceinline__ void gload_lds16(const bf16* g, bf16* l) {
  __builtin_amdgcn_global_load_lds((__attribute__((address_space(1))) void*)(g),
                                   (__attribute__((address_space(3))) void*)(l),
                                   16, 0, 0);
}

// ---------------- cast fp32 -> bf16 (vectorized) ----------------
__global__ void cast_bf16_k(const float* __restrict__ src, bf16* __restrict__ dst, int n) {
  int i = (blockIdx.x * blockDim.x + threadIdx.x) * 4;
  if (i >= n) return;
  float4 v = *(const float4*)(src + i);
  dst[i + 0] = (bf16)v.x;
  dst[i + 1] = (bf16)v.y;
  dst[i + 2] = (bf16)v.z;
  dst[i + 3] = (bf16)v.w;
}

// ---------------- transpose + cast for the 4 weight matrices ----------------
__global__ void transpose4_k(const float* __restrict__ W0, const float* __restrict__ W1,
                             const float* __restrict__ W2, const float* __restrict__ W3,
                             bf16* __restrict__ dst_base) {
  const int z = blockIdx.z;
  const float* src = (z == 0) ? W0 : (z == 1) ? W1 : (z == 2) ? W2 : W3;
  bf16* dst = dst_base + (size_t)z * (1024 * 1024);
  __shared__ float t[32][33];
  const int c0 = blockIdx.x * 32, r0 = blockIdx.y * 32;
  const int x = threadIdx.x, y = threadIdx.y;
  #pragma unroll
  for (int j = 0; j < 32; j += 8) t[y + j][x] = src[(size_t)(r0 + y + j) * 1024 + c0 + x];
  __syncthreads();
  #pragma unroll
  for (int j = 0; j < 32; j += 8)
    dst[(size_t)(c0 + y + j) * 1024 + r0 + x] = (bf16)t[x][y + j];
}

// ---------------- 64 x (NI*64) tile bf16 GEMM, double-buffered 2-phase ----------------
// A: [M,1024] bf16; Bt: [Ncols,1024] bf16 (=B^T). mode 0: QKV epilogue (col>>10
// selects Q/K/V region; V written transposed). mode 2: fp32 out + bias.
template <int NI>
__global__ __launch_bounds__(256) void gemm_k(
    const bf16* __restrict__ A, const bf16* __restrict__ Bt,
    bf16* __restrict__ QKV, float* __restrict__ Of,
    const float* __restrict__ bias, const int mode) {
  constexpr int K = 1024;
  const int row0 = blockIdx.x * 64;
  const int col0 = blockIdx.y * (NI * 64);

  __shared__ bf16 As[2][64 * 32];
  __shared__ bf16 Bs[2][NI * 64 * 32];

  const int tid = threadIdx.x;
  const int lane = tid & 63;
  const int wid = tid >> 6;
  const int lr = lane & 15;
  const int lk = (lane >> 4) * 8;
  const int sr = lane >> 2;
  const int sc = (lane & 3) * 8;

  f32x4 acc[4][NI];
  #pragma unroll
  for (int a = 0; a < 4; ++a)
    #pragma unroll
    for (int b = 0; b < NI; ++b) acc[a][b] = (f32x4){0.f, 0.f, 0.f, 0.f};

  auto stg = [&](int bb, int k0_) {
    gload_lds16(A + (size_t)(row0 + wid * 16 + sr) * K + k0_ + sc, &As[bb][wid * 512]);
    #pragma unroll
    for (int q = 0; q < NI; ++q)
      gload_lds16(Bt + (size_t)(col0 + wid * NI * 16 + q * 16 + sr) * K + k0_ + sc,
                  &Bs[bb][wid * NI * 512 + q * 512]);
  };

  stg(0, 0);
  for (int t = 0; t < K / 32; ++t) {
    __syncthreads();                      // drains vmcnt -> buf[t&1] staged
    if (t + 1 < K / 32) stg((t + 1) & 1, (t + 1) * 32);
    const bf16* as = &As[t & 1][0];
    const bf16* bs = &Bs[t & 1][0];
    bf16x8 af[4], bfv[NI];
    #pragma unroll
    for (int mi = 0; mi < 4; ++mi) af[mi] = *(const bf16x8*)&as[(mi * 16 + lr) * 32 + lk];
    #pragma unroll
    for (int ni = 0; ni < NI; ++ni)
      bfv[ni] = *(const bf16x8*)&bs[(wid * NI * 16 + ni * 16 + lr) * 32 + lk];
    #pragma unroll
    for (int mi = 0; mi < 4; ++mi)
      #pragma unroll
      for (int ni = 0; ni < NI; ++ni)
        acc[mi][ni] = MFMA16(af[mi], bfv[ni], acc[mi][ni]);
  }

  #pragma unroll
  for (int mi = 0; mi < 4; ++mi) {
    #pragma unroll
    for (int ni = 0; ni < NI; ++ni) {
      #pragma unroll
      for (int r = 0; r < 4; ++r) {
        const int row = row0 + mi * 16 + (lane >> 4) * 4 + r;
        const int col = col0 + wid * NI * 16 + ni * 16 + lr;
        const float v = acc[mi][ni][r];
        if (mode == 2) {
          Of[(size_t)row * 1024 + col] = v + bias[col];
        } else {
          const int b = row >> 10, i = row & 1023;
          const int which = col >> 10, cc = col & 1023;
          const int h = cc >> 6, d = cc & 63;
          if (which < 2)
            QKV[(size_t)which * 2097152 + (((size_t)(b * 16 + h)) * 1024 + i) * 64 + d] = (bf16)v;
          else
            QKV[(size_t)2 * 2097152 + (((size_t)(b * 16 + h)) * 64 + d) * 1024 + i] = (bf16)v;
        }
      }
    }
  }
}

// ---------------- causal flash attention, chunked split-K partials ----------------
// 40 chunks per bh, each <=4 key-blocks, LPT-ordered (size-4 chunks first).
// Chunk c of qb covers kb in [4c, min(qb, 4c+3)]. Partials: unnormalized O + m,l.
__device__ const int CH_QB[40] = {3,4,5,6,7,7,8,8,9,9,10,10,11,11,11,12,12,12,13,13,13,
                                  14,14,14,15,15,15,15, 2,6,10,14, 1,5,9,13, 0,4,8,12};
__device__ const int CH_K0[40] = {0,0,0,0,0,4,0,4,0,4,0,4,0,4,8,0,4,8,0,4,8,
                                  0,4,8,0,4,8,12, 0,4,8,12, 0,4,8,12, 0,4,8,12};

__global__ __launch_bounds__(256, 4) void attn_kernel(
    const bf16* __restrict__ Qh, const bf16* __restrict__ Kh,
    const bf16* __restrict__ Vt, const bf16* __restrict__ Eb,
    float* __restrict__ OP, float* __restrict__ MP, float* __restrict__ LP) {
  constexpr int N = 1024;
  const int bh = blockIdx.y;
  const int qb = CH_QB[blockIdx.x];
  const int kb0 = CH_K0[blockIdx.x];
  const int kb1 = min(qb, kb0 + 3);
  const int i0 = qb * 64;

  const bf16* Qp = Qh + (size_t)bh * N * 64;
  const bf16* Kp = Kh + (size_t)bh * N * 64;
  const bf16* Vp = Vt + (size_t)bh * 64 * N;

  __shared__ bf16 Ks[2][64 * 64];
  __shared__ bf16 Vs[2][64 * 64];
  __shared__ bf16 Ps[4][16 * 64];

  const int tid = threadIdx.x;
  const int lane = tid & 63;
  const int wid = tid >> 6;
  const int lr = lane & 15;
  const int g  = lane >> 4;

  const int srow   = lane >> 3;
  const int schunk = (lane & 7) ^ (srow & 7);

  bf16x8 qf[2];
  {
    const bf16* qrow = Qp + (size_t)(i0 + wid * 16 + lr) * 64 + g * 8;
    qf[0] = *(const bf16x8*)(qrow);
    qf[1] = *(const bf16x8*)(qrow + 32);
  }

  float m_r[4], l_r[4];
  f32x4 oacc[4];
  #pragma unroll
  for (int r = 0; r < 4; ++r) {
    m_r[r] = -3e38f;
    l_r[r] = 0.f;
    oacc[r] = (f32x4){0.f, 0.f, 0.f, 0.f};
  }

  const int sib = 3 - wid;
  const int iw0 = i0 + wid * 16;

  #define STAGE_KV(b, j0_)                                                             \
    {                                                                                  \
      const int rb0 = wid * 8, rb1 = 32 + wid * 8;                                     \
      gload_lds16(Kp + (size_t)((j0_) + rb0 + srow) * 64 + schunk * 8, &Ks[b][rb0 * 64]); \
      gload_lds16(Kp + (size_t)((j0_) + rb1 + srow) * 64 + schunk * 8, &Ks[b][rb1 * 64]); \
      gload_lds16(Vp + (size_t)(rb0 + srow) * 1024 + (j0_) + schunk * 8, &Vs[b][rb0 * 64]); \
      gload_lds16(Vp + (size_t)(rb1 + srow) * 1024 + (j0_) + schunk * 8, &Vs[b][rb1 * 64]); \
    }

  STAGE_KV(0, kb0 * 64);

  for (int kb = kb0; kb <= kb1; ++kb) {
    const int j0 = kb * 64;
    const int cur = (kb - kb0) & 1;
    __syncthreads();
    if (kb < kb1) STAGE_KV(cur ^ 1, j0 + 64);

    const bf16* kbuf = &Ks[cur][0];
    const bf16* vbuf = &Vs[cur][0];

    // issue E-fragment loads early (L2-hot); consumed after QK^T
    const int rbase = (N - 64) + j0 - i0;
    bf16x8 eA[5], eB[5];
    #pragma unroll
    for (int s5 = 0; s5 < 5; ++s5) {
      const bf16* ep = Eb + (size_t)(rbase + (sib + s5) * 16 + lr) * 64 + g * 8;
      eA[s5] = *(const bf16x8*)(ep);
      eB[s5] = *(const bf16x8*)(ep + 32);
    }

    // --- Q @ K^T (swizzled LDS reads) ---
    f32x4 sa[4];
    #pragma unroll
    for (int ni = 0; ni < 4; ++ni) sa[ni] = (f32x4){0.f, 0.f, 0.f, 0.f};
    __builtin_amdgcn_s_setprio(1);
    #pragma unroll
    for (int ni = 0; ni < 4; ++ni)
      #pragma unroll
      for (int kk = 0; kk < 2; ++kk) {
        const int row = ni * 16 + lr;
        bf16x8 kf = *(const bf16x8*)&kbuf[row * 64 + ((kk * 32 + g * 8) ^ ((lr & 7) << 3))];
        sa[ni] = MFMA16(qf[kk], kf, sa[ni]);
      }

    // --- Q @ E-window^T, 5 fragments ---
    f32x4 ea[5];
    #pragma unroll
    for (int s5 = 0; s5 < 5; ++s5) {
      ea[s5] = (f32x4){0.f, 0.f, 0.f, 0.f};
      ea[s5] = MFMA16(qf[0], eA[s5], ea[s5]);
      ea[s5] = MFMA16(qf[1], eB[s5], ea[s5]);
    }
    __builtin_amdgcn_s_setprio(0);

    // --- skew gather via lane shuffle ---
    float smax[4] = {-3e38f, -3e38f, -3e38f, -3e38f};
    #pragma unroll
    for (int r = 0; r < 4; ++r) {
      const int di = g * 4 + r;
      const int sl = (g << 4) | ((lr - di - 1) & 15);
      const float sh0 = __shfl(ea[0][r], sl);
      const float sh1 = __shfl(ea[1][r], sl);
      const float sh2 = __shfl(ea[2][r], sl);
      const float sh3 = __shfl(ea[3][r], sl);
      const float sh4 = __shfl(ea[4][r], sl);
      const bool hi = (lr > di);
      const float rel[4] = {hi ? sh1 : sh0, hi ? sh2 : sh1, hi ? sh3 : sh2, hi ? sh4 : sh3};
      const int ig = iw0 + di;
      #pragma unroll
      for (int ni = 0; ni < 4; ++ni) {
        float sv = (sa[ni][r] + rel[ni]) * 0.125f;
        sv = (j0 + ni * 16 + lr > ig) ? -1e30f : sv;
        sa[ni][r] = sv;
        smax[r] = fmaxf(smax[r], sv);
      }
    }
    #pragma unroll
    for (int off = 1; off < 16; off <<= 1)
      #pragma unroll
      for (int r = 0; r < 4; ++r)
        smax[r] = fmaxf(smax[r], __shfl_xor(smax[r], off));

    float corr[4], lb[4] = {0.f, 0.f, 0.f, 0.f};
    #pragma unroll
    for (int r = 0; r < 4; ++r) {
      const float mn = fmaxf(m_r[r], smax[r]);
      corr[r] = __expf(m_r[r] - mn);
      m_r[r] = mn;
    }
    #pragma unroll
    for (int r = 0; r < 4; ++r) {
      const int di = g * 4 + r;
      #pragma unroll
      for (int ni = 0; ni < 4; ++ni) {
        const float p = __expf(sa[ni][r] - m_r[r]);
        lb[r] += p;
        Ps[wid][di * 64 + ((ni * 16 + lr) ^ ((di & 7) << 3))] = (bf16)p;
      }
    }
    #pragma unroll
    for (int off = 1; off < 16; off <<= 1)
      #pragma unroll
      for (int r = 0; r < 4; ++r)
        lb[r] += __shfl_xor(lb[r], off);
    #pragma unroll
    for (int r = 0; r < 4; ++r) l_r[r] = l_r[r] * corr[r] + lb[r];
    #pragma unroll
    for (int nd = 0; nd < 4; ++nd)
      #pragma unroll
      for (int r = 0; r < 4; ++r)
        oacc[nd][r] *= corr[r];

    // --- P @ V ---
    bf16x8 pf[2];
    pf[0] = *(const bf16x8*)&Ps[wid][lr * 64 + ((g * 8) ^ ((lr & 7) << 3))];
    pf[1] = *(const bf16x8*)&Ps[wid][lr * 64 + ((32 + g * 8) ^ ((lr & 7) << 3))];
    __builtin_amdgcn_s_setprio(1);
    #pragma unroll
    for (int nd = 0; nd < 4; ++nd)
      #pragma unroll
      for (int kk = 0; kk < 2; ++kk) {
        const int row = nd * 16 + lr;
        bf16x8 vf = *(const bf16x8*)&vbuf[row * 64 + ((kk * 32 + g * 8) ^ ((lr & 7) << 3))];
        oacc[nd] = MFMA16(pf[kk], vf, oacc[nd]);
      }
    __builtin_amdgcn_s_setprio(0);
  }
  #undef STAGE_KV

  // partial epilogue: unnormalized O + m,l
  const int p = (bh * 16 + qb) * 4 + (kb0 >> 2);
  float* Op = OP + (size_t)p * 4096;
  #pragma unroll
  for (int nd = 0; nd < 4; ++nd)
    #pragma unroll
    for (int r = 0; r < 4; ++r)
      Op[(size_t)(wid * 16 + g * 4 + r) * 64 + nd * 16 + lr] = oacc[nd][r];
  if (lr == 0) {
    #pragma unroll
    for (int r = 0; r < 4; ++r) {
      MP[p * 64 + wid * 16 + g * 4 + r] = m_r[r];
      LP[p * 64 + wid * 16 + g * 4 + r] = l_r[r];
    }
  }
}

// ---------------- merge split-K partials (<=4) -> AO bf16 ----------------
__global__ __launch_bounds__(256) void merge_k(const float* __restrict__ OP,
                                               const float* __restrict__ MP,
                                               const float* __restrict__ LP,
                                               bf16* __restrict__ AO) {
  const int bh = blockIdx.x;     // 32
  const int qb = blockIdx.y;     // 16
  const int np = (qb >> 2) + 1;
  const int tid = threadIdx.x;
  const int row = tid >> 2;
  const int c0 = (tid & 3) * 16;
  const int p0 = (bh * 16 + qb) * 4;

  float m = -3e38f;
  for (int c = 0; c < np; ++c) m = fmaxf(m, MP[(p0 + c) * 64 + row]);

  float o[16];
  #pragma unroll
  for (int j = 0; j < 16; ++j) o[j] = 0.f;
  float l = 0.f;
  for (int c = 0; c < np; ++c) {
    const float a = __expf(MP[(p0 + c) * 64 + row] - m);
    l += LP[(p0 + c) * 64 + row] * a;
    const float* Oc = OP + (size_t)(p0 + c) * 4096 + row * 64 + c0;
    #pragma unroll
    for (int j = 0; j < 16; j += 4) {
      const f32x4 v = *(const f32x4*)&Oc[j];
      o[j + 0] += v[0] * a;
      o[j + 1] += v[1] * a;
      o[j + 2] += v[2] * a;
      o[j + 3] += v[3] * a;
    }
  }
  const float inv = 1.f / l;

  const int b = bh >> 4, h = bh & 15;
  bf16* dst = AO + ((size_t)(b * 1024) + qb * 64 + row) * 1024 + h * 64 + c0;
  #pragma unroll
  for (int j = 0; j < 16; ++j) dst[j] = (bf16)(o[j] * inv);
}

// ---------------- launch ----------------
extern "C" void kernel_launch(void* const* d_in, const int* in_sizes, int n_in,
                              void* d_out, int out_size, void* d_ws, size_t ws_size,
                              hipStream_t stream) {
  const float* x  = (const float*)d_in[0];
  const float* E  = (const float*)d_in[1];
  // d_in[2] = mask (causal by construction)
  const float* Wq = (const float*)d_in[3];
  const float* Wk = (const float*)d_in[4];
  const float* Wv = (const float*)d_in[5];
  const float* Wo = (const float*)d_in[6];
  const float* bo = (const float*)d_in[7];

  bf16* xb  = (bf16*)d_ws;               // 4 MiB
  bf16* Wqt = xb + 2048 * 1024;          // 8 MiB (Wq,Wk,Wv,Wo transposed, contiguous)
  bf16* Wot = Wqt + 3 * 1024 * 1024;
  bf16* Eb  = Wqt + 4 * 1024 * 1024;     // 256 KiB
  bf16* Qh  = Eb + 2048 * 64;            // 3 x 4 MiB (Q, K, V^T)
  bf16* AO  = Qh + 3 * 2048 * 1024;      // 4 MiB
  float* OP = (float*)(AO + 2048 * 1024); // 2048 slots x 4096 f32 = 32 MiB
  float* MPp = OP + (size_t)2048 * 4096;  // 512 KiB
  float* LPp = MPp + 2048 * 64;
  float* out = (float*)d_out;

  cast_bf16_k<<<dim3(2048), dim3(256), 0, stream>>>(x, xb, 2048 * 1024);
  cast_bf16_k<<<dim3(128), dim3(256), 0, stream>>>(E, Eb, 2047 * 64);
  transpose4_k<<<dim3(32, 32, 4), dim3(32, 8), 0, stream>>>(Wq, Wk, Wv, Wo, Wqt);

  // fused QKV projection: [2048,1024] @ [3072,1024]^T
  gemm_k<2><<<dim3(32, 24), dim3(256), 0, stream>>>(xb, Wqt, Qh, nullptr, nullptr, 0);

  attn_kernel<<<dim3(40, 32), dim3(256), 0, stream>>>(
      Qh, Qh + 2048 * 1024, Qh + 2 * 2048 * 1024, Eb, OP, MPp, LPp);

  merge_k<<<dim3(32, 16), dim3(256), 0, stream>>>(OP, MPp, LPp, AO);

  // output projection: fp32 + bias, 64x64 tiles -> 512 blocks
  gemm_k<1><<<dim3(32, 16), dim3(256), 0, stream>>>(AO, Wot, nullptr, out, bo, 2);
}